// Round 6
// baseline (235.981 us; speedup 1.0000x reference)
//
#include <hip/hip_runtime.h>

typedef short  short4v __attribute__((ext_vector_type(4)));
typedef short  short8v __attribute__((ext_vector_type(8)));
typedef __bf16 bf16x8  __attribute__((ext_vector_type(8)));
typedef float  f32x4   __attribute__((ext_vector_type(4)));
typedef float  float4v __attribute__((ext_vector_type(4)));

__device__ __forceinline__ short f2bf(float f) {
  unsigned u = __builtin_bit_cast(unsigned, f);
  u += 0x7fffu + ((u >> 16) & 1u);   // RNE
  return (short)(u >> 16);
}
__device__ __forceinline__ bf16x8 ld8(const short* p) {
  return __builtin_bit_cast(bf16x8, *reinterpret_cast<const short8v*>(p));
}

// ---------- fp32 -> bf16 convert ----------
__global__ __launch_bounds__(256) void k_cvt(const float* __restrict__ in,
                                             short* __restrict__ out, int n4) {
  int i = blockIdx.x * 256 + threadIdx.x;
  if (i >= n4) return;
  float4v v = *reinterpret_cast<const float4v*>(in + (long)i * 4);
  short4v o;
  o[0] = f2bf(v[0]); o[1] = f2bf(v[1]); o[2] = f2bf(v[2]); o[3] = f2bf(v[3]);
  *reinterpret_cast<short4v*>(out + (long)i * 4) = o;
}

// 3 weight matrices fp32->bf16 (Wq, Wk, Wo)
__global__ __launch_bounds__(256) void k_cvtw(const float* __restrict__ w0,
    const float* __restrict__ w1, const float* __restrict__ w2,
    short* __restrict__ o0, short* __restrict__ o1, short* __restrict__ o2) {
  const float* in = blockIdx.y == 0 ? w0 : blockIdx.y == 1 ? w1 : w2;
  short* out = blockIdx.y == 0 ? o0 : blockIdx.y == 1 ? o1 : o2;
  int i = blockIdx.x * 256 + threadIdx.x;
  float4v v = *reinterpret_cast<const float4v*>(in + (long)i * 4);
  short4v o;
  o[0] = f2bf(v[0]); o[1] = f2bf(v[1]); o[2] = f2bf(v[2]); o[3] = f2bf(v[3]);
  *reinterpret_cast<short4v*>(out + (long)i * 4) = o;
}

// transposed convert: Wv f32 [e,d] -> wvT bf16 [d,e]  (1024x1024)
__global__ __launch_bounds__(256) void k_cvtT(const float* __restrict__ in,
                                              short* __restrict__ out) {
  __shared__ float tile[16][17];
  const int lx = threadIdx.x & 15, ly = threadIdx.x >> 4;
  const int bx = blockIdx.x << 4, by = blockIdx.y << 4;
  tile[ly][lx] = in[(long)(by + ly) * 1024 + bx + lx];
  __syncthreads();
  out[(long)(bx + ly) * 1024 + by + lx] = f2bf(tile[lx][ly]);
}

// bv' = Wo (f32 [o,e]) * bv (f32 [e]) -> f32 [o]
__global__ __launch_bounds__(256) void k_matvec(const float* __restrict__ W,
    const float* __restrict__ v, float* __restrict__ o) {
  const int row = blockIdx.x * 4 + (threadIdx.x >> 6), lane = threadIdx.x & 63;
  float s = 0.f;
#pragma unroll
  for (int j = 0; j < 16; ++j)
    s += W[(long)row * 1024 + j * 64 + lane] * v[j * 64 + lane];
#pragma unroll
  for (int off = 32; off; off >>= 1) s += __shfl_xor(s, off);
  if (lane == 0) o[row] = s;
}

// concat biases: o[0..1023]=a, o[1024..2047]=b
__global__ __launch_bounds__(256) void k_bcat(const float* __restrict__ a,
    const float* __restrict__ b, float* __restrict__ o) {
  int i = blockIdx.x * 256 + threadIdx.x;
  o[i] = i < 1024 ? a[i] : b[i - 1024];
}

// ---------- 2-phase double-buffered m97-core GEMM: C = A[M,K]*B[N,K]^T ----------
// 128x128 tile, 256 thr = 4 waves (2x2), 4x4 16x16x32 frags/wave, BK=64.
// T3-minimal pipeline: stage(t+1) issued BEFORE ds_read+MFMA of tile t;
// one __syncthreads per tile (implicit vmcnt(0) is the drain). LDS 64KB ->
// 2 blocks/CU. lda/ldb allow strided operands (fused QK buffer, V'^T view).
// MODE 0: bf16 out, no bias          MODE 2: bf16 + col-bias b0p
// MODE 5: bf16 + row-bias b0p        MODE 3: exp epilogue + psum (b1p)
// MODE 4: f32 out + col-bias b0p, row-scale 1/L from psum (b1p)
template <int MODE>
__global__ __launch_bounds__(256, 2) void k_gemm(
    const short* __restrict__ A, const short* __restrict__ B,
    const float* __restrict__ b0p, float* __restrict__ b1p,
    void* __restrict__ C0,
    int K, int lda, int ldb, long sA, long sB, long sC, int ldC) {
  __shared__ __align__(16) short lsA[2][8192];
  __shared__ __align__(16) short lsB[2][8192];
  __shared__ float invL[128];
  const int tid = threadIdx.x;
  const int lane = tid & 63, wid = tid >> 6;
  const int wr = wid >> 1, wc = wid & 1;
  const int fr = lane & 15, fq = lane >> 4;
  const int bm = blockIdx.x * 128, bn = blockIdx.y * 128;
  const short* Ab = A + (long)blockIdx.z * sA;
  const short* Bb = B + (long)blockIdx.z * sB;
  const int nt = K >> 6;

  if constexpr (MODE == 4) {
    if (tid < 128) {
      const float* pr = b1p + ((long)blockIdx.z * 2048 + bm + tid) * 32;
      float s = 0.f;
#pragma unroll
      for (int j = 0; j < 32; ++j) s += pr[j];
      invL[tid] = 1.0f / s;
    }
  }

  auto stage = [&](int kt, int buf) {
#pragma unroll
    for (int c = 0; c < 4; ++c) {
      const int idx = c * 256 + tid;
      const int row = idx >> 3, colh = (idx & 7) << 3;
      const short* ga = Ab + (long)(bm + row) * lda + kt + colh;
      const short* gb = Bb + (long)(bn + row) * ldb + kt + colh;
      __builtin_amdgcn_global_load_lds(
          (const __attribute__((address_space(1))) void*)ga,
          (__attribute__((address_space(3))) void*)&lsA[buf][idx * 8], 16, 0, 0);
      __builtin_amdgcn_global_load_lds(
          (const __attribute__((address_space(1))) void*)gb,
          (__attribute__((address_space(3))) void*)&lsB[buf][idx * 8], 16, 0, 0);
    }
  };

  f32x4 acc[4][4] = {};

  stage(0, 0);
  __syncthreads();
  for (int t = 0; t < nt; ++t) {
    if (t + 1 < nt) stage((t + 1) << 6, (t + 1) & 1);
    const short* cA = lsA[t & 1];
    const short* cB = lsB[t & 1];
#pragma unroll
    for (int ks = 0; ks < 64; ks += 32) {
      bf16x8 a[4], b[4];
#pragma unroll
      for (int m = 0; m < 4; ++m)
        a[m] = ld8(&cA[(wr * 64 + m * 16 + fr) * 64 + ks + fq * 8]);
#pragma unroll
      for (int n = 0; n < 4; ++n)
        b[n] = ld8(&cB[(wc * 64 + n * 16 + fr) * 64 + ks + fq * 8]);
#pragma unroll
      for (int m = 0; m < 4; ++m)
#pragma unroll
        for (int n = 0; n < 4; ++n)
          acc[m][n] = __builtin_amdgcn_mfma_f32_16x16x32_bf16(a[m], b[n], acc[m][n], 0, 0, 0);
    }
    __syncthreads();
  }

  // ---- epilogues ----
  if constexpr (MODE == 3) {
    // P_unnorm = exp(s/32) bf16 + per-row partial sums into psum[b][row][32]
    short* O = (short*)C0 + (long)blockIdx.z * sC;
#pragma unroll
    for (int m = 0; m < 4; ++m) {
#pragma unroll
      for (int i = 0; i < 4; ++i) {
        const int row = bm + wr * 64 + m * 16 + fq * 4 + i;
        float rs = 0.f;
#pragma unroll
        for (int n = 0; n < 4; ++n) {
          float e = __expf(acc[m][n][i] * 0.03125f);
          O[(long)row * ldC + bn + wc * 64 + n * 16 + fr] = f2bf(e);
          rs += e;
        }
        rs += __shfl_xor(rs, 1); rs += __shfl_xor(rs, 2);
        rs += __shfl_xor(rs, 4); rs += __shfl_xor(rs, 8);
        if (fr == 0)
          b1p[((long)blockIdx.z * 2048 + row) * 32 + (blockIdx.y << 1) + wc] = rs;
      }
    }
  } else {
#pragma unroll
    for (int n = 0; n < 4; ++n) {
      const int coll = wc * 64 + n * 16 + fr;
#pragma unroll
      for (int m = 0; m < 4; ++m) {
        const int rl0 = wr * 64 + m * 16 + fq * 4;   // local row
#pragma unroll
        for (int i = 0; i < 4; ++i) {
          const float vacc = acc[m][n][i];
          const long row = bm + rl0 + i, col = bn + coll;
          if constexpr (MODE == 0) {
            ((short*)C0)[row * ldC + col] = f2bf(vacc);
          } else if constexpr (MODE == 2) {
            ((short*)C0)[row * ldC + col] = f2bf(vacc + b0p[col]);
          } else if constexpr (MODE == 5) {
            ((short*)C0)[row * ldC + col] = f2bf(vacc + b0p[row]);
          } else {  // MODE 4
            float* O = (float*)C0 + (long)blockIdx.z * sC;
            O[row * ldC + col] = vacc * invL[rl0 + i] + b0p[col];
          }
        }
      }
    }
  }
}

// ---------- launcher ----------
extern "C" void kernel_launch(void* const* d_in, const int* in_sizes, int n_in,
                              void* d_out, int out_size, void* d_ws, size_t ws_size,
                              hipStream_t stream) {
  const float* x  = (const float*)d_in[0];
  const float* Wq = (const float*)d_in[1];
  const float* bq = (const float*)d_in[2];
  const float* Wk = (const float*)d_in[3];
  const float* bk = (const float*)d_in[4];
  const float* Wv = (const float*)d_in[5];
  const float* bv = (const float*)d_in[6];
  const float* Wo = (const float*)d_in[7];
  const float* bo = (const float*)d_in[8];

  // ws layout: every region fully overwritten before read each call.
  char* ws = (char*)d_ws;
  short* xb   = (short*)ws; ws += 8192L * 1024 * 2;     // x bf16
  short* wqkb = (short*)ws; ws += 2048L * 1024 * 2;     // [Wq; Wk] bf16
  short* wob  = (short*)ws; ws += 1024L * 1024 * 2;     // Wo bf16
  short* wvT  = (short*)ws; ws += 1024L * 1024 * 2;     // Wv^T bf16 [d,e]
  short* wv2b = (short*)ws; ws += 1024L * 1024 * 2;     // Wv'' = Wo*Wv bf16
  short* qkb  = (short*)ws; ws += 8192L * 2048 * 2;     // [Q | K] rows of 2048
  short* vTp  = (short*)ws; ws += 1024L * 8192 * 2;     // V'^T [e][b*2048+s]
  short* Sc   = (short*)ws; ws += 4L * 2048 * 2048 * 2; // exp-scores
  float* psum = (float*)ws; ws += 4L * 2048 * 32 * 4;   // row partial sums
  float* bqk  = (float*)ws; ws += 2048L * 4;            // [bq; bk]
  float* bvp  = (float*)ws; ws += 1024L * 4;            // bv' = Wo*bv

  dim3 b256(256);
  k_cvt<<<8192, b256, 0, stream>>>(x, xb, 2097152);
  k_cvtw<<<dim3(1024, 3, 1), b256, 0, stream>>>(
      Wq, Wk, Wo, wqkb, wqkb + 1024L * 1024, wob);
  k_cvtT<<<dim3(64, 64, 1), b256, 0, stream>>>(Wv, wvT);
  k_bcat<<<8, b256, 0, stream>>>(bq, bk, bqk);
  k_matvec<<<256, b256, 0, stream>>>(Wo, bv, bvp);

  // Wv'' = Wo*Wv = wob * wvT^T
  k_gemm<0><<<dim3(8, 8, 1), b256, 0, stream>>>(
      wob, wvT, nullptr, nullptr, wv2b, 1024, 1024, 1024, 0, 0, 0, 1024);
  // [Q|K] = x * [Wq;Wk]^T + [bq;bk]   (M=8192, N=2048, K=1024)
  k_gemm<2><<<dim3(64, 16, 1), b256, 0, stream>>>(
      xb, wqkb, bqk, nullptr, qkb, 1024, 1024, 1024, 0, 0, 0, 2048);
  // V'^T[e][b*2048+s] = Wv'' * x^T + bv'[e]  (M=1024, N=8192, K=1024)
  k_gemm<5><<<dim3(8, 64, 1), b256, 0, stream>>>(
      wv2b, xb, bvp, nullptr, vTp, 1024, 1024, 1024, 0, 0, 0, 8192);
  // exp-scores[b] = exp(Q[b]*K[b]^T / 32) + psum  (M=N=2048, K=1024)
  k_gemm<3><<<dim3(16, 16, 4), b256, 0, stream>>>(
      qkb, qkb + 1024, nullptr, psum, Sc,
      1024, 2048, 2048, 2048L * 2048, 2048L * 2048, 2048L * 2048, 2048);
  // out = (P_unnorm * V') / L + bo -> fp32 d_out  (M=2048, N=1024, K=2048)
  k_gemm<4><<<dim3(16, 8, 4), b256, 0, stream>>>(
      Sc, vTp, bo, psum, (float*)d_out,
      2048, 2048, 8192, 2048L * 2048, 2048, 2048L * 1024, 1024);
}